// Round 8
// baseline (203.042 us; speedup 1.0000x reference)
//
#include <hip/hip_runtime.h>
#include <stdint.h>

// Problem constants
#define Bc 2
#define Sc 2048
#define Ec 1024
#define Hc 16
#define Dc 64
#define Mc (Bc*Sc)   // 4096 rows

typedef __attribute__((ext_vector_type(4))) float f32x4;
typedef __attribute__((ext_vector_type(8))) short bf16x8v;
typedef __attribute__((ext_vector_type(4))) short bf16x4v;

// 0.125 * log2(e): folded into Q at the GEMM epilogue -> scores exit QK^T in exp2 domain
#define SCL 0.1803368801f

__device__ __forceinline__ unsigned short f2bf(float f){
  unsigned int u = __float_as_uint(f);
  u += 0x7FFFu + ((u >> 16) & 1u);     // RNE
  return (unsigned short)(u >> 16);
}

// packed RNE f32x2 -> bf16x2 (gfx950 VOP3); a -> low16, b -> high16
__device__ __forceinline__ unsigned int cvt_pk_bf16(float a, float b){
  unsigned int d;
  asm("v_cvt_pk_bf16_f32 %0, %1, %2" : "=v"(d) : "v"(a), "v"(b));
  return d;
}

// raw v_exp_f32 (2^x); skips the OCML wrapper's edge-case VALU ops
__device__ __forceinline__ float fast_exp2(float x){
  float r;
  asm("v_exp_f32 %0, %1" : "=v"(r) : "v"(x));
  return r;
}

#define GLDS(src, dst) __builtin_amdgcn_global_load_lds( \
    (const __attribute__((address_space(1))) void*)(src), \
    (__attribute__((address_space(3))) void*)(dst), 16, 0, 0)

// counted vmem wait: steady-state phases never drain to 0 (T4)
#define VMCNT(n) do { asm volatile("s_waitcnt vmcnt(" #n ")" ::: "memory"); \
                      __builtin_amdgcn_sched_barrier(0); } while(0)
#define BARRIER() do { __builtin_amdgcn_s_barrier(); \
                       __builtin_amdgcn_sched_barrier(0); } while(0)

// -------- fused prep: X fp32->bf16 (blocks 0..4095) + W->WT bf16 (blocks 4096..5119) ----
__global__ __launch_bounds__(256) void k_prep(const float* __restrict__ X,
                                              unsigned short* __restrict__ Xb,
                                              const float* __restrict__ W0, const float* __restrict__ W1,
                                              const float* __restrict__ W2, const float* __restrict__ W3,
                                              unsigned short* __restrict__ WT4){
  __shared__ float st[64][65];
  int bx = blockIdx.x, t = threadIdx.x;
  if (bx < 4096){
    int i = bx*256 + t;
    float4 v = ((const float4*)X)[i];
    ushort4 o;
    o.x = f2bf(v.x); o.y = f2bf(v.y); o.z = f2bf(v.z); o.w = f2bf(v.w);
    ((ushort4*)Xb)[i] = o;
  } else {
    int id = bx - 4096;
    int z = id >> 8, rem = id & 255;
    int k0 = (rem >> 4)*64, n0 = (rem & 15)*64;
    const float* W = (z==0)?W0 : (z==1)?W1 : (z==2)?W2 : W3;
    unsigned short* o = WT4 + (size_t)z * Ec * Ec;
    #pragma unroll
    for (int i=0;i<16;i++){ int lin=i*256+t; int r=lin>>6, c=lin&63;
      st[r][c] = W[(size_t)(k0+r)*Ec + n0+c]; }
    __syncthreads();
    #pragma unroll
    for (int i=0;i<16;i++){ int lin=i*256+t; int nn=lin>>6, kk=lin&63;
      o[(size_t)(n0+nn)*Ec + k0+kk] = f2bf(st[kk][nn]); }
  }
}

// ------------- FUSED QKV GEMM: BK=64 (XOR-swizzled LDS), depth-2 counted-vmcnt pipeline ---------
// BM=128, BN=64. Outputs: z=0 Q*SCL [B][H][S][D], z=1 K [B][H][S][D], z=2 V^T [B][H][D][S].
// V^T is stored with 8B halves swapped within each 16B s-chunk on rows with (d&8):
// store col = s0 ^ ((d&8)?4:0). Consumed by k_attn's bank-conflict-free V-read.
__global__ __launch_bounds__(256,2) void k_qkv(const unsigned short* __restrict__ A,
                                               const unsigned short* __restrict__ WT4,
                                               const float* __restrict__ bq,
                                               const float* __restrict__ bk,
                                               const float* __restrict__ bv,
                                               unsigned short* __restrict__ QKV){
  __shared__ unsigned short sA[2][128*64];     // 16 KB per buf, swizzled: slot p holds chunk p^(row&7)
  __shared__ unsigned short sB[2][3][64*64];   // 8 KB per slice
  int bm = blockIdx.y, bn = blockIdx.x;        // bn: 0..15 over N=1024
  int t = threadIdx.x, w = t>>6, lane = t&63, quad = lane>>4, m16 = lane&15;
  int wm = w>>1, wn = w&1, sw = m16 & 7;
  f32x4 acc[3][4][2];
  #pragma unroll
  for (int z=0;z<3;z++)
    #pragma unroll
    for (int i=0;i<4;i++)
      #pragma unroll
      for (int j=0;j<2;j++) acc[z][i][j] = (f32x4){0.f,0.f,0.f,0.f};

  auto stage = [&](int kt, int buf){
    #pragma unroll
    for (int i=0;i<4;i++){                     // A: 128x64 = 1024 chunks, 4/thread
      int cb = (w*4 + i)*64;
      int L = cb + lane;
      int row = L>>3, c = (L&7) ^ (row&7);
      GLDS(A + (size_t)(bm*128 + row)*Ec + kt*64 + c*8, &sA[buf][0] + cb*8);
    }
    #pragma unroll
    for (int z=0;z<3;z++)
      #pragma unroll
      for (int i=0;i<2;i++){                   // each B slice: 64x64 = 512 chunks, 2/thread
        int cb = (w*2 + i)*64;
        int L = cb + lane;
        int row = L>>3, c = (L&7) ^ (row&7);
        GLDS(WT4 + (size_t)z*Ec*Ec + (size_t)(bn*64 + row)*Ec + kt*64 + c*8,
             &sB[buf][z][0] + cb*8);
      }
  };

  stage(0, 0);
  stage(1, 1);
  for (int kt=0; kt<Ec/64; ++kt){
    int cur = kt & 1;
    if (kt < Ec/64 - 1) VMCNT(10);        // stage(kt) landed; stage(kt+1) still flying
    else                VMCNT(0);         // tail: only stage(NT-1) outstanding
    BARRIER();
    bf16x8v af[4][2];
    #pragma unroll
    for (int s=0;s<4;s++){
      int row = wm*64 + s*16 + m16;
      af[s][0] = *(const bf16x8v*)(&sA[cur][0] + row*64 + ((quad  )^sw)*8);
      af[s][1] = *(const bf16x8v*)(&sA[cur][0] + row*64 + ((quad+4)^sw)*8);
    }
    #pragma unroll
    for (int z=0;z<3;z++){
      bf16x8v bfr[2][2];
      #pragma unroll
      for (int sn=0;sn<2;sn++){
        int rowb = wn*32 + sn*16 + m16;
        bfr[sn][0] = *(const bf16x8v*)(&sB[cur][z][0] + rowb*64 + ((quad  )^sw)*8);
        bfr[sn][1] = *(const bf16x8v*)(&sB[cur][z][0] + rowb*64 + ((quad+4)^sw)*8);
      }
      #pragma unroll
      for (int sm=0;sm<4;sm++)
        #pragma unroll
        for (int sn=0;sn<2;sn++){
          acc[z][sm][sn] = __builtin_amdgcn_mfma_f32_16x16x32_bf16(af[sm][0], bfr[sn][0], acc[z][sm][sn], 0,0,0);
          acc[z][sm][sn] = __builtin_amdgcn_mfma_f32_16x16x32_bf16(af[sm][1], bfr[sn][1], acc[z][sm][sn], 0,0,0);
        }
    }
    BARRIER();                            // all waves done reading buf cur
    if (kt+2 < Ec/64) stage(kt+2, cur);   // overwrite it with tile kt+2
  }
  // epilogue: C/D layout row = quad*4+r, col = lane&15
  #pragma unroll
  for (int z=0;z<3;z++){
    const float* bias = (z==0)?bq : (z==1)?bk : bv;
    unsigned short* Out = QKV + (size_t)z * (size_t)Mc * Ec;
    #pragma unroll
    for (int sm=0;sm<4;sm++){
      int row0 = bm*128 + wm*64 + sm*16 + quad*4;
      int bidx = row0 >> 11;
      #pragma unroll
      for (int sn=0;sn<2;sn++){
        int col = bn*64 + wn*32 + sn*16 + m16;
        float bb = bias[col];
        int h = col >> 6, d = col & 63;
        if (z == 2){
          int s0 = (row0 & (Sc-1)) ^ ((d & 8) ? 4 : 0);   // half-swap rows d&8 (bank fix)
          ushort4 pk;
          pk.x = f2bf(acc[z][sm][sn][0] + bb);
          pk.y = f2bf(acc[z][sm][sn][1] + bb);
          pk.z = f2bf(acc[z][sm][sn][2] + bb);
          pk.w = f2bf(acc[z][sm][sn][3] + bb);
          *(ushort4*)(Out + (((size_t)bidx*Hc + h)*Dc + d)*Sc + s0) = pk;
        } else {
          float sc_ = (z==0) ? SCL : 1.0f;   // fold 0.125*log2e into Q
          #pragma unroll
          for (int r=0;r<4;r++){
            int s = (row0 + r) & (Sc-1);
            Out[(((size_t)bidx*Hc + h)*Sc + s)*Dc + d] = f2bf((acc[z][sm][sn][r] + bb)*sc_);
          }
        }
      }
    }
  }
}

// ------------- out-proj GEMM: BK=64 swizzled, depth-2 counted-vmcnt, fp32 out [4096][1024] ------
__global__ __launch_bounds__(256,3) void k_gemm1(const unsigned short* __restrict__ A,
                                                 const unsigned short* __restrict__ WT,
                                                 const float* __restrict__ bias,
                                                 float* __restrict__ Out){
  __shared__ unsigned short sA[2][128*64];
  __shared__ unsigned short sB[2][64*64];
  int bm = blockIdx.y, bn = blockIdx.x;
  int t = threadIdx.x, w = t>>6, lane = t&63, quad = lane>>4, m16 = lane&15;
  int wm = w>>1, wn = w&1, sw = m16 & 7;
  f32x4 acc[4][2];
  #pragma unroll
  for (int i=0;i<4;i++)
    #pragma unroll
    for (int j=0;j<2;j++) acc[i][j] = (f32x4){0.f,0.f,0.f,0.f};

  auto stage = [&](int kt, int buf){
    #pragma unroll
    for (int i=0;i<4;i++){
      int cb = (w*4 + i)*64;
      int L = cb + lane;
      int row = L>>3, c = (L&7) ^ (row&7);
      GLDS(A + (size_t)(bm*128 + row)*Ec + kt*64 + c*8, &sA[buf][0] + cb*8);
    }
    #pragma unroll
    for (int i=0;i<2;i++){
      int cb = (w*2 + i)*64;
      int L = cb + lane;
      int row = L>>3, c = (L&7) ^ (row&7);
      GLDS(WT + (size_t)(bn*64 + row)*Ec + kt*64 + c*8, &sB[buf][0] + cb*8);
    }
  };

  stage(0, 0);
  stage(1, 1);
  for (int kt=0; kt<Ec/64; ++kt){
    int cur = kt & 1;
    if (kt < Ec/64 - 1) VMCNT(6);
    else                VMCNT(0);
    BARRIER();
    bf16x8v af[4][2], bfr[2][2];
    #pragma unroll
    for (int s=0;s<4;s++){
      int row = wm*64 + s*16 + m16;
      af[s][0] = *(const bf16x8v*)(&sA[cur][0] + row*64 + ((quad  )^sw)*8);
      af[s][1] = *(const bf16x8v*)(&sA[cur][0] + row*64 + ((quad+4)^sw)*8);
    }
    #pragma unroll
    for (int sn=0;sn<2;sn++){
      int rowb = wn*32 + sn*16 + m16;
      bfr[sn][0] = *(const bf16x8v*)(&sB[cur][0] + rowb*64 + ((quad  )^sw)*8);
      bfr[sn][1] = *(const bf16x8v*)(&sB[cur][0] + rowb*64 + ((quad+4)^sw)*8);
    }
    #pragma unroll
    for (int sm=0;sm<4;sm++)
      #pragma unroll
      for (int sn=0;sn<2;sn++){
        acc[sm][sn] = __builtin_amdgcn_mfma_f32_16x16x32_bf16(af[sm][0], bfr[sn][0], acc[sm][sn], 0,0,0);
        acc[sm][sn] = __builtin_amdgcn_mfma_f32_16x16x32_bf16(af[sm][1], bfr[sn][1], acc[sm][sn], 0,0,0);
      }
    BARRIER();
    if (kt+2 < Ec/64) stage(kt+2, cur);
  }
  #pragma unroll
  for (int sm=0;sm<4;sm++){
    int row0 = bm*128 + wm*64 + sm*16 + quad*4;
    #pragma unroll
    for (int sn=0;sn<2;sn++){
      int col = bn*64 + wn*32 + sn*16 + m16;
      float bb = bias[col];
      #pragma unroll
      for (int r=0;r<4;r++)
        Out[(size_t)(row0+r)*Ec + col] = acc[sm][sn][r] + bb;
    }
  }
}

// ------------- flash attention: DUAL q-tiles per wave (K/V fragments read once, used twice) -----
// Each wave owns q-tiles 2p (A) and 2p+1 (B). K-frags and V-frags are q-independent, so a
// single LDS read feeds both tiles' MFMA chains: LDS reads / staging / barriers per FLOP halve.
// All phases except the last (kt = 2p+1) are dual.
__device__ __forceinline__ void attn_dual(const unsigned short* sK, const unsigned short* sVT,
                                          bf16x8v qA0, bf16x8v qA1, bf16x8v qB0, bf16x8v qB1,
                                          bf16x4v ones4, f32x4& liA, f32x4& liB,
                                          f32x4* OaA, f32x4* OaB,
                                          int kbase, int qwA, int qwB, int quad, int m16, bool doA){
  int sw = m16 & 7;
  // S^T[j][q]: C-layout j=kbase+sm*16+quad*4+r, q=qw+m16. kf shared by both tiles.
  f32x4 scA[4], scB[4];
  #pragma unroll
  for (int sm=0;sm<4;sm++){
    int row = sm*16 + m16;
    bf16x8v kf0 = *(const bf16x8v*)(sK + row*64 + ((quad  )^sw)*8);
    bf16x8v kf1 = *(const bf16x8v*)(sK + row*64 + ((quad+4)^sw)*8);
    f32x4 b = (f32x4){0.f,0.f,0.f,0.f};
    b = __builtin_amdgcn_mfma_f32_16x16x32_bf16(kf0, qB0, b, 0,0,0);
    b = __builtin_amdgcn_mfma_f32_16x16x32_bf16(kf1, qB1, b, 0,0,0);
    scB[sm] = b;
    if (doA){
      f32x4 a = (f32x4){0.f,0.f,0.f,0.f};
      a = __builtin_amdgcn_mfma_f32_16x16x32_bf16(kf0, qA0, a, 0,0,0);
      a = __builtin_amdgcn_mfma_f32_16x16x32_bf16(kf1, qA1, a, 0,0,0);
      scA[sm] = a;
    }
  }
  // exp2 + causal mask (diagonal tiles only), then pack to in-lane K16 A-frags
  bf16x4v a16A[4], a16B[4];
  bool maskB = (kbase + 63 > qwB);
  #pragma unroll
  for (int sm=0;sm<4;sm++){
    #pragma unroll
    for (int r=0;r<4;r++){
      float pv = fast_exp2(scB[sm][r]);
      if (maskB){
        int kg = kbase + sm*16 + quad*4 + r;
        pv = (kg <= qwB + m16) ? pv : 0.0f;
      }
      scB[sm][r] = pv;
    }
    uint2 pk;
    pk.x = cvt_pk_bf16(scB[sm][0], scB[sm][1]);
    pk.y = cvt_pk_bf16(scB[sm][2], scB[sm][3]);
    a16B[sm] = __builtin_bit_cast(bf16x4v, pk);
  }
  if (doA){
    bool maskA = (kbase + 63 > qwA);
    #pragma unroll
    for (int sm=0;sm<4;sm++){
      #pragma unroll
      for (int r=0;r<4;r++){
        float pv = fast_exp2(scA[sm][r]);
        if (maskA){
          int kg = kbase + sm*16 + quad*4 + r;
          pv = (kg <= qwA + m16) ? pv : 0.0f;
        }
        scA[sm][r] = pv;
      }
      uint2 pk;
      pk.x = cvt_pk_bf16(scA[sm][0], scA[sm][1]);
      pk.y = cvt_pk_bf16(scA[sm][2], scA[sm][3]);
      a16A[sm] = __builtin_bit_cast(bf16x4v, pk);
    }
  }

  // li[q] += sum_j P[q][j] via ones-MFMA (K16, C-layout row q=quad*4+r)
  #pragma unroll
  for (int sm=0;sm<4;sm++){
    liB = __builtin_amdgcn_mfma_f32_16x16x16bf16_1k(a16B[sm], ones4, liB, 0,0,0);
    if (doA) liA = __builtin_amdgcn_mfma_f32_16x16x16bf16_1k(a16A[sm], ones4, liA, 0,0,0);
  }

  // O[q][d] += P·V ; one V-frag read feeds BOTH tiles' PV MFMAs.
  int half = ((quad & 1) ^ (m16 >> 3)) * 4;
  #pragma unroll
  for (int tt=0;tt<4;tt++){
    int rowv = tt*16 + m16;
    #pragma unroll
    for (int sm=0;sm<4;sm++){
      uint2 vv = *(const uint2*)(sVT + rowv*64 + (((sm*2 + (quad>>1))^sw)*8) + half);
      bf16x4v vf = __builtin_bit_cast(bf16x4v, vv);
      OaB[tt] = __builtin_amdgcn_mfma_f32_16x16x16bf16_1k(a16B[sm], vf, OaB[tt], 0,0,0);
      if (doA) OaA[tt] = __builtin_amdgcn_mfma_f32_16x16x16bf16_1k(a16A[sm], vf, OaA[tt], 0,0,0);
    }
  }
}

// grid 512 blocks × 256 threads. Block p owns q-tiles {2p, 2p+1}.
//  * XCD pin: bh ≡ bid (mod 8) (256%8==0 keeps CU-mates on one XCD, same head).
//  * balance: CU-mates (bid, bid+256) get pair-indices (j, 15-j) -> phases (2j+2)+(32-2j) = 34 const.
__global__ __launch_bounds__(256,2) void k_attn(const unsigned short* __restrict__ Qb,
                                                const unsigned short* __restrict__ Kb,
                                                const unsigned short* __restrict__ VTb,
                                                unsigned short* __restrict__ Ob){
  __shared__ unsigned short sK [2][64*64]; // [j][d], 16B chunks XOR-swizzled by row&7
  __shared__ unsigned short sVT[2][64*64]; // [d][j], same swizzle (+ producer half-swap on d&8)
  int bid = (int)blockIdx.x;
  int g = bid >> 3;
  int bh = (bid & 7) | ((g & 3) << 3);      // head pinned to XCD = bid%8
  int j  = g >> 2;                          // 0..15
  int p  = (j & 8) ? (15 - (j & 7)) : j;    // pair index; CU-mates get (j, 15-j)
  int qtA = 2*p, qtB = 2*p + 1;
  size_t base = (size_t)bh * Sc * Dc;
  const unsigned short* Q  = Qb  + base;
  const unsigned short* K  = Kb  + base;
  const unsigned short* VT = VTb + base;   // [d][s]
  int t = threadIdx.x, w = t>>6, lane = t&63, quad = lane>>4, m16 = lane&15;
  int qwA = qtA*64 + w*16;
  int qwB = qtB*64 + w*16;

  bf16x8v qA0 = *(const bf16x8v*)(Q + (size_t)(qwA + m16)*Dc + quad*8);
  bf16x8v qA1 = *(const bf16x8v*)(Q + (size_t)(qwA + m16)*Dc + 32 + quad*8);
  bf16x8v qB0 = *(const bf16x8v*)(Q + (size_t)(qwB + m16)*Dc + quad*8);
  bf16x8v qB1 = *(const bf16x8v*)(Q + (size_t)(qwB + m16)*Dc + 32 + quad*8);

  bf16x4v ones4;
  #pragma unroll
  for (int i=0;i<4;i++) ones4[i] = (short)0x3F80;   // bf16 1.0

  f32x4 OaA[4], OaB[4];
  #pragma unroll
  for (int i=0;i<4;i++){ OaA[i] = (f32x4){0.f,0.f,0.f,0.f}; OaB[i] = (f32x4){0.f,0.f,0.f,0.f}; }
  f32x4 liA = (f32x4){0.f,0.f,0.f,0.f}, liB = (f32x4){0.f,0.f,0.f,0.f};

  auto stage = [&](int kt, int buf){
    int kbase = kt*64;
    #pragma unroll
    for (int i=0;i<2;i++){
      int cb = (w*2 + i)*64;              // wave-uniform chunk base
      int L = cb + lane;
      int row = L>>3, pp = L&7, c = pp ^ (row&7);
      GLDS(K  + (size_t)(kbase+row)*Dc + c*8,        &sK[buf][0]  + cb*8);
      GLDS(VT + (size_t)row*Sc + kbase + c*8,        &sVT[buf][0] + cb*8);
    }
  };

  // pipelined: stage(kt+1) issues right after the barrier publishing stage(kt).
  stage(0, 0);
  for (int kt=0; kt<=qtB; ++kt){
    int cur = kt & 1;
    __syncthreads();
    if (kt < qtB) stage(kt+1, cur^1);
    attn_dual(&sK[cur][0], &sVT[cur][0], qA0, qA1, qB0, qB1, ones4,
              liA, liB, OaA, OaB, kt*64, qwA, qwB, quad, m16, kt <= qtA);
  }

  // epilogue: O rows s = qw+quad*4+r, cols e = h*64 + tt*16 + m16
  int b = bh >> 4, h = bh & 15;
  float iA[4], iB[4];
  #pragma unroll
  for (int r=0;r<4;r++){ iA[r] = 1.0f/liA[r]; iB[r] = 1.0f/liB[r]; }
  #pragma unroll
  for (int tt=0;tt<4;tt++)
    #pragma unroll
    for (int r=0;r<4;r++){
      int e = h*64 + tt*16 + m16;
      int sA_ = qwA + quad*4 + r;
      int sB_ = qwB + quad*4 + r;
      Ob[((size_t)b*Sc + sA_)*Ec + e] = f2bf(OaA[tt][r]*iA[r]);
      Ob[((size_t)b*Sc + sB_)*Ec + e] = f2bf(OaB[tt][r]*iB[r]);
    }
}

extern "C" void kernel_launch(void* const* d_in, const int* in_sizes, int n_in,
                              void* d_out, int out_size, void* d_ws, size_t ws_size,
                              hipStream_t stream){
  const float* X  = (const float*)d_in[0];
  const float* Wq = (const float*)d_in[1];
  const float* bq = (const float*)d_in[2];
  const float* Wk = (const float*)d_in[3];
  const float* bk = (const float*)d_in[4];
  const float* Wv = (const float*)d_in[5];
  const float* bv = (const float*)d_in[6];
  const float* Wo = (const float*)d_in[7];
  const float* bo = (const float*)d_in[8];

  uint8_t* ws = (uint8_t*)d_ws;
  unsigned short* Xb  = (unsigned short*)(ws);                    // 8 MB
  unsigned short* WT4 = (unsigned short*)(ws + (size_t)(8u<<20)); // 8 MB (WqT,WkT,WvT,WoT)
  unsigned short* QKV = (unsigned short*)(ws + (size_t)(16u<<20));// 24 MB (Q,K,V^T)
  unsigned short* ATT = (unsigned short*)(ws + (size_t)(40u<<20));// 8 MB

  k_prep<<<dim3(5120), 256, 0, stream>>>(X, Xb, Wq, Wk, Wv, Wo, WT4);
  k_qkv<<<dim3(16,32), 256, 0, stream>>>(Xb, WT4, bq, bk, bv, QKV);
  k_attn<<<dim3(512), 256, 0, stream>>>(QKV, QKV + (size_t)Mc*Ec, QKV + 2*(size_t)Mc*Ec, ATT);
  k_gemm1<<<dim3(16,32), 256, 0, stream>>>(ATT, WT4 + (size_t)3*Ec*Ec, bo, (float*)d_out);
}

// Round 9
// 169.460 us; speedup vs baseline: 1.1982x; 1.1982x over previous
//
#include <hip/hip_runtime.h>
#include <stdint.h>

// Problem constants
#define Bc 2
#define Sc 2048
#define Ec 1024
#define Hc 16
#define Dc 64
#define Mc (Bc*Sc)   // 4096 rows

typedef __attribute__((ext_vector_type(4))) float f32x4;
typedef __attribute__((ext_vector_type(8))) short bf16x8v;
typedef __attribute__((ext_vector_type(4))) short bf16x4v;

// 0.125 * log2(e): folded into Q at the GEMM epilogue -> scores exit QK^T in exp2 domain
#define SCL 0.1803368801f

__device__ __forceinline__ unsigned short f2bf(float f){
  unsigned int u = __float_as_uint(f);
  u += 0x7FFFu + ((u >> 16) & 1u);     // RNE
  return (unsigned short)(u >> 16);
}

// packed RNE f32x2 -> bf16x2 (gfx950 VOP3); a -> low16, b -> high16
__device__ __forceinline__ unsigned int cvt_pk_bf16(float a, float b){
  unsigned int d;
  asm("v_cvt_pk_bf16_f32 %0, %1, %2" : "=v"(d) : "v"(a), "v"(b));
  return d;
}

// raw v_exp_f32 (2^x); skips the OCML wrapper's edge-case VALU ops
__device__ __forceinline__ float fast_exp2(float x){
  float r;
  asm("v_exp_f32 %0, %1" : "=v"(r) : "v"(x));
  return r;
}

#define GLDS(src, dst) __builtin_amdgcn_global_load_lds( \
    (const __attribute__((address_space(1))) void*)(src), \
    (__attribute__((address_space(3))) void*)(dst), 16, 0, 0)

// counted vmem wait: steady-state phases never drain to 0 (T4)
#define VMCNT(n) do { asm volatile("s_waitcnt vmcnt(" #n ")" ::: "memory"); \
                      __builtin_amdgcn_sched_barrier(0); } while(0)
#define BARRIER() do { __builtin_amdgcn_s_barrier(); \
                       __builtin_amdgcn_sched_barrier(0); } while(0)

// -------- fused prep: X fp32->bf16 (blocks 0..4095) + W->WT bf16 (blocks 4096..5119) ----
__global__ __launch_bounds__(256) void k_prep(const float* __restrict__ X,
                                              unsigned short* __restrict__ Xb,
                                              const float* __restrict__ W0, const float* __restrict__ W1,
                                              const float* __restrict__ W2, const float* __restrict__ W3,
                                              unsigned short* __restrict__ WT4){
  __shared__ float st[64][65];
  int bx = blockIdx.x, t = threadIdx.x;
  if (bx < 4096){
    int i = bx*256 + t;
    float4 v = ((const float4*)X)[i];
    ushort4 o;
    o.x = f2bf(v.x); o.y = f2bf(v.y); o.z = f2bf(v.z); o.w = f2bf(v.w);
    ((ushort4*)Xb)[i] = o;
  } else {
    int id = bx - 4096;
    int z = id >> 8, rem = id & 255;
    int k0 = (rem >> 4)*64, n0 = (rem & 15)*64;
    const float* W = (z==0)?W0 : (z==1)?W1 : (z==2)?W2 : W3;
    unsigned short* o = WT4 + (size_t)z * Ec * Ec;
    #pragma unroll
    for (int i=0;i<16;i++){ int lin=i*256+t; int r=lin>>6, c=lin&63;
      st[r][c] = W[(size_t)(k0+r)*Ec + n0+c]; }
    __syncthreads();
    #pragma unroll
    for (int i=0;i<16;i++){ int lin=i*256+t; int nn=lin>>6, kk=lin&63;
      o[(size_t)(n0+nn)*Ec + k0+kk] = f2bf(st[kk][nn]); }
  }
}

// ------------- FUSED QKV GEMM: BK=64 (XOR-swizzled LDS), depth-2 counted-vmcnt pipeline ---------
// BM=128, BN=64. Outputs: z=0 Q*SCL [B][H][S][D], z=1 K [B][H][S][D], z=2 V^T [B][H][D][S].
// V^T is stored with 8B halves swapped within each 16B s-chunk on rows with (d&8):
// store col = s0 ^ ((d&8)?4:0). Consumed by k_attn's bank-conflict-free V-read.
__global__ __launch_bounds__(256,2) void k_qkv(const unsigned short* __restrict__ A,
                                               const unsigned short* __restrict__ WT4,
                                               const float* __restrict__ bq,
                                               const float* __restrict__ bk,
                                               const float* __restrict__ bv,
                                               unsigned short* __restrict__ QKV){
  __shared__ unsigned short sA[2][128*64];     // 16 KB per buf, swizzled: slot p holds chunk p^(row&7)
  __shared__ unsigned short sB[2][3][64*64];   // 8 KB per slice
  int bm = blockIdx.y, bn = blockIdx.x;        // bn: 0..15 over N=1024
  int t = threadIdx.x, w = t>>6, lane = t&63, quad = lane>>4, m16 = lane&15;
  int wm = w>>1, wn = w&1, sw = m16 & 7;
  f32x4 acc[3][4][2];
  #pragma unroll
  for (int z=0;z<3;z++)
    #pragma unroll
    for (int i=0;i<4;i++)
      #pragma unroll
      for (int j=0;j<2;j++) acc[z][i][j] = (f32x4){0.f,0.f,0.f,0.f};

  auto stage = [&](int kt, int buf){
    #pragma unroll
    for (int i=0;i<4;i++){                     // A: 128x64 = 1024 chunks, 4/thread
      int cb = (w*4 + i)*64;
      int L = cb + lane;
      int row = L>>3, c = (L&7) ^ (row&7);
      GLDS(A + (size_t)(bm*128 + row)*Ec + kt*64 + c*8, &sA[buf][0] + cb*8);
    }
    #pragma unroll
    for (int z=0;z<3;z++)
      #pragma unroll
      for (int i=0;i<2;i++){                   // each B slice: 64x64 = 512 chunks, 2/thread
        int cb = (w*2 + i)*64;
        int L = cb + lane;
        int row = L>>3, c = (L&7) ^ (row&7);
        GLDS(WT4 + (size_t)z*Ec*Ec + (size_t)(bn*64 + row)*Ec + kt*64 + c*8,
             &sB[buf][z][0] + cb*8);
      }
  };

  stage(0, 0);
  stage(1, 1);
  for (int kt=0; kt<Ec/64; ++kt){
    int cur = kt & 1;
    if (kt < Ec/64 - 1) VMCNT(10);        // stage(kt) landed; stage(kt+1) still flying
    else                VMCNT(0);         // tail: only stage(NT-1) outstanding
    BARRIER();
    bf16x8v af[4][2];
    #pragma unroll
    for (int s=0;s<4;s++){
      int row = wm*64 + s*16 + m16;
      af[s][0] = *(const bf16x8v*)(&sA[cur][0] + row*64 + ((quad  )^sw)*8);
      af[s][1] = *(const bf16x8v*)(&sA[cur][0] + row*64 + ((quad+4)^sw)*8);
    }
    #pragma unroll
    for (int z=0;z<3;z++){
      bf16x8v bfr[2][2];
      #pragma unroll
      for (int sn=0;sn<2;sn++){
        int rowb = wn*32 + sn*16 + m16;
        bfr[sn][0] = *(const bf16x8v*)(&sB[cur][z][0] + rowb*64 + ((quad  )^sw)*8);
        bfr[sn][1] = *(const bf16x8v*)(&sB[cur][z][0] + rowb*64 + ((quad+4)^sw)*8);
      }
      #pragma unroll
      for (int sm=0;sm<4;sm++)
        #pragma unroll
        for (int sn=0;sn<2;sn++){
          acc[z][sm][sn] = __builtin_amdgcn_mfma_f32_16x16x32_bf16(af[sm][0], bfr[sn][0], acc[z][sm][sn], 0,0,0);
          acc[z][sm][sn] = __builtin_amdgcn_mfma_f32_16x16x32_bf16(af[sm][1], bfr[sn][1], acc[z][sm][sn], 0,0,0);
        }
    }
    BARRIER();                            // all waves done reading buf cur
    if (kt+2 < Ec/64) stage(kt+2, cur);   // overwrite it with tile kt+2
  }
  // epilogue: C/D layout row = quad*4+r, col = lane&15
  #pragma unroll
  for (int z=0;z<3;z++){
    const float* bias = (z==0)?bq : (z==1)?bk : bv;
    unsigned short* Out = QKV + (size_t)z * (size_t)Mc * Ec;
    #pragma unroll
    for (int sm=0;sm<4;sm++){
      int row0 = bm*128 + wm*64 + sm*16 + quad*4;
      int bidx = row0 >> 11;
      #pragma unroll
      for (int sn=0;sn<2;sn++){
        int col = bn*64 + wn*32 + sn*16 + m16;
        float bb = bias[col];
        int h = col >> 6, d = col & 63;
        if (z == 2){
          int s0 = (row0 & (Sc-1)) ^ ((d & 8) ? 4 : 0);   // half-swap rows d&8 (bank fix)
          ushort4 pk;
          pk.x = f2bf(acc[z][sm][sn][0] + bb);
          pk.y = f2bf(acc[z][sm][sn][1] + bb);
          pk.z = f2bf(acc[z][sm][sn][2] + bb);
          pk.w = f2bf(acc[z][sm][sn][3] + bb);
          *(ushort4*)(Out + (((size_t)bidx*Hc + h)*Dc + d)*Sc + s0) = pk;
        } else {
          float sc_ = (z==0) ? SCL : 1.0f;   // fold 0.125*log2e into Q
          #pragma unroll
          for (int r=0;r<4;r++){
            int s = (row0 + r) & (Sc-1);
            Out[(((size_t)bidx*Hc + h)*Sc + s)*Dc + d] = f2bf((acc[z][sm][sn][r] + bb)*sc_);
          }
        }
      }
    }
  }
}

// ------------- out-proj GEMM: BK=64 swizzled, depth-2 counted-vmcnt, fp32 out [4096][1024] ------
__global__ __launch_bounds__(256,3) void k_gemm1(const unsigned short* __restrict__ A,
                                                 const unsigned short* __restrict__ WT,
                                                 const float* __restrict__ bias,
                                                 float* __restrict__ Out){
  __shared__ unsigned short sA[2][128*64];
  __shared__ unsigned short sB[2][64*64];
  int bm = blockIdx.y, bn = blockIdx.x;
  int t = threadIdx.x, w = t>>6, lane = t&63, quad = lane>>4, m16 = lane&15;
  int wm = w>>1, wn = w&1, sw = m16 & 7;
  f32x4 acc[4][2];
  #pragma unroll
  for (int i=0;i<4;i++)
    #pragma unroll
    for (int j=0;j<2;j++) acc[i][j] = (f32x4){0.f,0.f,0.f,0.f};

  auto stage = [&](int kt, int buf){
    #pragma unroll
    for (int i=0;i<4;i++){
      int cb = (w*4 + i)*64;
      int L = cb + lane;
      int row = L>>3, c = (L&7) ^ (row&7);
      GLDS(A + (size_t)(bm*128 + row)*Ec + kt*64 + c*8, &sA[buf][0] + cb*8);
    }
    #pragma unroll
    for (int i=0;i<2;i++){
      int cb = (w*2 + i)*64;
      int L = cb + lane;
      int row = L>>3, c = (L&7) ^ (row&7);
      GLDS(WT + (size_t)(bn*64 + row)*Ec + kt*64 + c*8, &sB[buf][0] + cb*8);
    }
  };

  stage(0, 0);
  stage(1, 1);
  for (int kt=0; kt<Ec/64; ++kt){
    int cur = kt & 1;
    if (kt < Ec/64 - 1) VMCNT(6);
    else                VMCNT(0);
    BARRIER();
    bf16x8v af[4][2], bfr[2][2];
    #pragma unroll
    for (int s=0;s<4;s++){
      int row = wm*64 + s*16 + m16;
      af[s][0] = *(const bf16x8v*)(&sA[cur][0] + row*64 + ((quad  )^sw)*8);
      af[s][1] = *(const bf16x8v*)(&sA[cur][0] + row*64 + ((quad+4)^sw)*8);
    }
    #pragma unroll
    for (int sn=0;sn<2;sn++){
      int rowb = wn*32 + sn*16 + m16;
      bfr[sn][0] = *(const bf16x8v*)(&sB[cur][0] + rowb*64 + ((quad  )^sw)*8);
      bfr[sn][1] = *(const bf16x8v*)(&sB[cur][0] + rowb*64 + ((quad+4)^sw)*8);
    }
    #pragma unroll
    for (int sm=0;sm<4;sm++)
      #pragma unroll
      for (int sn=0;sn<2;sn++){
        acc[sm][sn] = __builtin_amdgcn_mfma_f32_16x16x32_bf16(af[sm][0], bfr[sn][0], acc[sm][sn], 0,0,0);
        acc[sm][sn] = __builtin_amdgcn_mfma_f32_16x16x32_bf16(af[sm][1], bfr[sn][1], acc[sm][sn], 0,0,0);
      }
    BARRIER();
    if (kt+2 < Ec/64) stage(kt+2, cur);
  }
  #pragma unroll
  for (int sm=0;sm<4;sm++){
    int row0 = bm*128 + wm*64 + sm*16 + quad*4;
    #pragma unroll
    for (int sn=0;sn<2;sn++){
      int col = bn*64 + wn*32 + sn*16 + m16;
      float bb = bias[col];
      #pragma unroll
      for (int r=0;r<4;r++)
        Out[(size_t)(row0+r)*Ec + col] = acc[sm][sn][r] + bb;
    }
  }
}

// ------------- flash attention: P in registers via K=16 PV MFMAs; conflict-free V-reads ---------
// (proven round-7 body; staging now depth-2 counted-vmcnt like the GEMMs)
__device__ __forceinline__ void attn_tile(const unsigned short* sK, const unsigned short* sVT,
                                          bf16x8v qf0, bf16x8v qf1,
                                          bf16x4v ones4, f32x4& li, f32x4* Oa,
                                          int kbase, int qw, int quad, int m16){
  int sw = m16 & 7;
  // S^T[j][q] = sum_d K[j][d] Q'[q][d]; C-layout: j=kbase+sm*16+quad*4+r, q=qw+m16
  f32x4 sc[4];
  #pragma unroll
  for (int sm=0;sm<4;sm++){
    int row = sm*16 + m16;
    bf16x8v kf0 = *(const bf16x8v*)(sK + row*64 + ((quad  )^sw)*8);
    bf16x8v kf1 = *(const bf16x8v*)(sK + row*64 + ((quad+4)^sw)*8);
    f32x4 a = (f32x4){0.f,0.f,0.f,0.f};
    a = __builtin_amdgcn_mfma_f32_16x16x32_bf16(kf0, qf0, a, 0,0,0);
    a = __builtin_amdgcn_mfma_f32_16x16x32_bf16(kf1, qf1, a, 0,0,0);
    sc[sm] = a;
  }
  // p = exp2(s); zero masked entries (diagonal tiles only)
  if (kbase + 63 > qw){
    #pragma unroll
    for (int sm=0;sm<4;sm++)
      #pragma unroll
      for (int r=0;r<4;r++){
        int kg = kbase + sm*16 + quad*4 + r;
        float p = fast_exp2(sc[sm][r]);
        sc[sm][r] = (kg <= qw + m16) ? p : 0.0f;
      }
  } else {
    #pragma unroll
    for (int sm=0;sm<4;sm++)
      #pragma unroll
      for (int r=0;r<4;r++) sc[sm][r] = fast_exp2(sc[sm][r]);
  }

  // in-lane A-frags for K=16 MFMAs: a16[sm] elem e = P[q=m16][j=sm*16+quad*4+e]
  bf16x4v a16[4];
  #pragma unroll
  for (int sm=0;sm<4;sm++){
    uint2 pk;
    pk.x = cvt_pk_bf16(sc[sm][0], sc[sm][1]);  // e0 low, e1 high
    pk.y = cvt_pk_bf16(sc[sm][2], sc[sm][3]);  // e2 low, e3 high
    a16[sm] = __builtin_bit_cast(bf16x4v, pk);
  }

  // li[q] += sum_j P[q][j] via ones-MFMA; C-layout row q=quad*4+r (matches O rows)
  #pragma unroll
  for (int sm=0;sm<4;sm++)
    li = __builtin_amdgcn_mfma_f32_16x16x16bf16_1k(a16[sm], ones4, li, 0,0,0);

  // O[q][d] += P·V ; B-frag B[k=j=quad*4+e][d=m16] = V^T[d=tt*16+m16][j=sm*16+quad*4+e]
  // half = (quad&1)^(m16>>3) matches the producer's d&8 half-swap (rowv bit3 = m16 bit3).
  int half = ((quad & 1) ^ (m16 >> 3)) * 4;
  #pragma unroll
  for (int tt=0;tt<4;tt++){
    int rowv = tt*16 + m16;
    #pragma unroll
    for (int sm=0;sm<4;sm++){
      uint2 vv = *(const uint2*)(sVT + rowv*64 + (((sm*2 + (quad>>1))^sw)*8) + half);
      Oa[tt] = __builtin_amdgcn_mfma_f32_16x16x16bf16_1k(a16[sm], __builtin_bit_cast(bf16x4v, vv), Oa[tt], 0,0,0);
    }
  }
}

// grid (32, 32) = 1024 blocks, 4 blocks/CU. XCD pin + balance mapping proven in round 2.
// Staging: depth-2 counted vmcnt — per-thread 4 GLDS/stage; steady-state wait vmcnt(4)
// retires exactly the older stage while the newer 4 loads stay in flight. All ds_reads
// are MFMA-consumed before the second barrier, so the kt+2 overwrite is race-free.
__global__ __launch_bounds__(256,4) void k_attn(const unsigned short* __restrict__ Qb,
                                                const unsigned short* __restrict__ Kb,
                                                const unsigned short* __restrict__ VTb,
                                                unsigned short* __restrict__ Ob){
  __shared__ unsigned short sK [2][64*64]; // [j][d], 16B chunks XOR-swizzled by row&7
  __shared__ unsigned short sVT[2][64*64]; // [d][j], same swizzle (+ producer half-swap on d&8)
  int bid = (int)blockIdx.x + 32*(int)blockIdx.y;
  int g = bid >> 3;
  int h3 = g >> 2;                          // 0..31
  int qt = (h3 & 8) ? (h3 ^ 7) : h3;        // balance involution
  int bh = (bid & 7) + ((g & 3) << 3);      // head pinned to XCD = bid%8
  size_t base = (size_t)bh * Sc * Dc;
  const unsigned short* Q  = Qb  + base;
  const unsigned short* K  = Kb  + base;
  const unsigned short* VT = VTb + base;   // [d][s]
  int t = threadIdx.x, w = t>>6, lane = t&63, quad = lane>>4, m16 = lane&15;
  int qw = qt*64 + w*16;

  bf16x8v q0 = *(const bf16x8v*)(Q + (size_t)(qw + m16)*Dc + quad*8);
  bf16x8v q1 = *(const bf16x8v*)(Q + (size_t)(qw + m16)*Dc + 32 + quad*8);

  bf16x4v ones4;
  #pragma unroll
  for (int i=0;i<4;i++) ones4[i] = (short)0x3F80;   // bf16 1.0

  f32x4 Oa[4];
  #pragma unroll
  for (int i=0;i<4;i++) Oa[i] = (f32x4){0.f,0.f,0.f,0.f};
  f32x4 li = (f32x4){0.f,0.f,0.f,0.f};

  auto stage = [&](int kt, int buf){
    int kbase = kt*64;
    #pragma unroll
    for (int i=0;i<2;i++){
      int cb = (w*2 + i)*64;              // wave-uniform chunk base
      int L = cb + lane;
      int row = L>>3, p = L&7, c = p ^ (row&7);
      GLDS(K  + (size_t)(kbase+row)*Dc + c*8,        &sK[buf][0]  + cb*8);
      GLDS(VT + (size_t)row*Sc + kbase + c*8,        &sVT[buf][0] + cb*8);
    }
  };

  stage(0, 0);
  if (qt >= 1) stage(1, 1);
  for (int kt=0; kt<=qt; ++kt){
    int cur = kt & 1;
    if (kt < qt) VMCNT(4);                // stage(kt) retired; stage(kt+1) still flying
    else         VMCNT(0);                // tail: only stage(qt) outstanding
    BARRIER();
    attn_tile(&sK[cur][0], &sVT[cur][0], q0, q1, ones4, li, Oa, kt*64, qw, quad, m16);
    BARRIER();                            // all waves done reading buf cur
    if (kt+2 <= qt) stage(kt+2, cur);     // overwrite it with tile kt+2
  }

  // epilogue: O rows s = qw+quad*4+r, cols e = h*64 + tt*16 + m16; li already per-row
  int b = bh >> 4, h = bh & 15;
  float iv[4];
  #pragma unroll
  for (int r=0;r<4;r++) iv[r] = 1.0f/li[r];
  #pragma unroll
  for (int tt=0;tt<4;tt++)
    #pragma unroll
    for (int r=0;r<4;r++){
      int e = h*64 + tt*16 + m16;
      int s = qw + quad*4 + r;
      Ob[((size_t)b*Sc + s)*Ec + e] = f2bf(Oa[tt][r]*iv[r]);
    }
}

extern "C" void kernel_launch(void* const* d_in, const int* in_sizes, int n_in,
                              void* d_out, int out_size, void* d_ws, size_t ws_size,
                              hipStream_t stream){
  const float* X  = (const float*)d_in[0];
  const float* Wq = (const float*)d_in[1];
  const float* bq = (const float*)d_in[2];
  const float* Wk = (const float*)d_in[3];
  const float* bk = (const float*)d_in[4];
  const float* Wv = (const float*)d_in[5];
  const float* bv = (const float*)d_in[6];
  const float* Wo = (const float*)d_in[7];
  const float* bo = (const float*)d_in[8];

  uint8_t* ws = (uint8_t*)d_ws;
  unsigned short* Xb  = (unsigned short*)(ws);                    // 8 MB
  unsigned short* WT4 = (unsigned short*)(ws + (size_t)(8u<<20)); // 8 MB (WqT,WkT,WvT,WoT)
  unsigned short* QKV = (unsigned short*)(ws + (size_t)(16u<<20));// 24 MB (Q,K,V^T)
  unsigned short* ATT = (unsigned short*)(ws + (size_t)(40u<<20));// 8 MB

  k_prep<<<dim3(5120), 256, 0, stream>>>(X, Xb, Wq, Wk, Wv, Wo, WT4);
  k_qkv<<<dim3(16,32), 256, 0, stream>>>(Xb, WT4, bq, bk, bv, QKV);
  k_attn<<<dim3(32,32), 256, 0, stream>>>(QKV, QKV + (size_t)Mc*Ec, QKV + 2*(size_t)Mc*Ec, ATT);
  k_gemm1<<<dim3(16,32), 256, 0, stream>>>(ATT, WT4 + (size_t)3*Ec*Ec, bo, (float*)d_out);
}

// Round 10
// 168.681 us; speedup vs baseline: 1.2037x; 1.0046x over previous
//
#include <hip/hip_runtime.h>
#include <stdint.h>

// Problem constants
#define Bc 2
#define Sc 2048
#define Ec 1024
#define Hc 16
#define Dc 64
#define Mc (Bc*Sc)   // 4096 rows

typedef __attribute__((ext_vector_type(4))) float f32x4;
typedef __attribute__((ext_vector_type(8))) short bf16x8v;
typedef __attribute__((ext_vector_type(4))) short bf16x4v;

// 0.125 * log2(e): folded into Q at the GEMM epilogue -> scores exit QK^T in exp2 domain
#define SCL 0.1803368801f

__device__ __forceinline__ unsigned short f2bf(float f){
  unsigned int u = __float_as_uint(f);
  u += 0x7FFFu + ((u >> 16) & 1u);     // RNE
  return (unsigned short)(u >> 16);
}

// packed RNE f32x2 -> bf16x2 (gfx950 VOP3); a -> low16, b -> high16
__device__ __forceinline__ unsigned int cvt_pk_bf16(float a, float b){
  unsigned int d;
  asm("v_cvt_pk_bf16_f32 %0, %1, %2" : "=v"(d) : "v"(a), "v"(b));
  return d;
}

// raw v_exp_f32 (2^x); skips the OCML wrapper's edge-case VALU ops
__device__ __forceinline__ float fast_exp2(float x){
  float r;
  asm("v_exp_f32 %0, %1" : "=v"(r) : "v"(x));
  return r;
}

#define GLDS(src, dst) __builtin_amdgcn_global_load_lds( \
    (const __attribute__((address_space(1))) void*)(src), \
    (__attribute__((address_space(3))) void*)(dst), 16, 0, 0)

// counted vmem wait: steady-state phases never drain to 0 (T4)
#define VMCNT(n) do { asm volatile("s_waitcnt vmcnt(" #n ")" ::: "memory"); \
                      __builtin_amdgcn_sched_barrier(0); } while(0)
#define BARRIER() do { __builtin_amdgcn_s_barrier(); \
                       __builtin_amdgcn_sched_barrier(0); } while(0)

// -------- fused prep: X fp32->bf16 (blocks 0..4095) + W->WT bf16 (blocks 4096..5119) ----
// Transpose stores now packed: 2 bf16 along k per uint (4B/lane, was 2B/lane scalar).
__global__ __launch_bounds__(256) void k_prep(const float* __restrict__ X,
                                              unsigned short* __restrict__ Xb,
                                              const float* __restrict__ W0, const float* __restrict__ W1,
                                              const float* __restrict__ W2, const float* __restrict__ W3,
                                              unsigned short* __restrict__ WT4){
  __shared__ float st[64][65];
  int bx = blockIdx.x, t = threadIdx.x;
  if (bx < 4096){
    int i = bx*256 + t;
    float4 v = ((const float4*)X)[i];
    ushort4 o;
    o.x = f2bf(v.x); o.y = f2bf(v.y); o.z = f2bf(v.z); o.w = f2bf(v.w);
    ((ushort4*)Xb)[i] = o;
  } else {
    int id = bx - 4096;
    int z = id >> 8, rem = id & 255;
    int k0 = (rem >> 4)*64, n0 = (rem & 15)*64;
    const float* W = (z==0)?W0 : (z==1)?W1 : (z==2)?W2 : W3;
    unsigned short* o = WT4 + (size_t)z * Ec * Ec;
    #pragma unroll
    for (int i=0;i<16;i++){ int lin=i*256+t; int r=lin>>6, c=lin&63;
      st[r][c] = W[(size_t)(k0+r)*Ec + n0+c]; }
    __syncthreads();
    // 2048 uint writes: lin = i*256+t in [0,2048); nn = lin>>5, kp = lin&31.
    // o[(n0+nn)*Ec + k0 + 2kp] <- pack(st[2kp][nn], st[2kp+1][nn]); LDS reads 2-way (free).
    #pragma unroll
    for (int i=0;i<8;i++){ int lin=i*256+t; int nn=lin>>5, kp=lin&31;
      unsigned int pk = cvt_pk_bf16(st[2*kp][nn], st[2*kp+1][nn]);
      *(unsigned int*)(o + (size_t)(n0+nn)*Ec + k0 + 2*kp) = pk; }
  }
}

// ------------- FUSED QKV GEMM: BK=64 (XOR-swizzled LDS), depth-2 counted-vmcnt pipeline ---------
// BM=128, BN=64. Outputs: z=0 Q*SCL [B][H][S][D], z=1 K [B][H][S][D], z=2 V^T [B][H][D][S].
// V^T is stored with 8B halves swapped within each 16B s-chunk on rows with (d&8):
// store col = s0 ^ ((d&8)?4:0). Consumed by k_attn's bank-conflict-free V-read.
__global__ __launch_bounds__(256,2) void k_qkv(const unsigned short* __restrict__ A,
                                               const unsigned short* __restrict__ WT4,
                                               const float* __restrict__ bq,
                                               const float* __restrict__ bk,
                                               const float* __restrict__ bv,
                                               unsigned short* __restrict__ QKV){
  __shared__ unsigned short sA[2][128*64];     // 16 KB per buf, swizzled: slot p holds chunk p^(row&7)
  __shared__ unsigned short sB[2][3][64*64];   // 8 KB per slice
  int bm = blockIdx.y, bn = blockIdx.x;        // bn: 0..15 over N=1024
  int t = threadIdx.x, w = t>>6, lane = t&63, quad = lane>>4, m16 = lane&15;
  int wm = w>>1, wn = w&1, sw = m16 & 7;
  f32x4 acc[3][4][2];
  #pragma unroll
  for (int z=0;z<3;z++)
    #pragma unroll
    for (int i=0;i<4;i++)
      #pragma unroll
      for (int j=0;j<2;j++) acc[z][i][j] = (f32x4){0.f,0.f,0.f,0.f};

  auto stage = [&](int kt, int buf){
    #pragma unroll
    for (int i=0;i<4;i++){                     // A: 128x64 = 1024 chunks, 4/thread
      int cb = (w*4 + i)*64;
      int L = cb + lane;
      int row = L>>3, c = (L&7) ^ (row&7);
      GLDS(A + (size_t)(bm*128 + row)*Ec + kt*64 + c*8, &sA[buf][0] + cb*8);
    }
    #pragma unroll
    for (int z=0;z<3;z++)
      #pragma unroll
      for (int i=0;i<2;i++){                   // each B slice: 64x64 = 512 chunks, 2/thread
        int cb = (w*2 + i)*64;
        int L = cb + lane;
        int row = L>>3, c = (L&7) ^ (row&7);
        GLDS(WT4 + (size_t)z*Ec*Ec + (size_t)(bn*64 + row)*Ec + kt*64 + c*8,
             &sB[buf][z][0] + cb*8);
      }
  };

  stage(0, 0);
  stage(1, 1);
  for (int kt=0; kt<Ec/64; ++kt){
    int cur = kt & 1;
    if (kt < Ec/64 - 1) VMCNT(10);        // stage(kt) landed; stage(kt+1) still flying
    else                VMCNT(0);         // tail: only stage(NT-1) outstanding
    BARRIER();
    bf16x8v af[4][2];
    #pragma unroll
    for (int s=0;s<4;s++){
      int row = wm*64 + s*16 + m16;
      af[s][0] = *(const bf16x8v*)(&sA[cur][0] + row*64 + ((quad  )^sw)*8);
      af[s][1] = *(const bf16x8v*)(&sA[cur][0] + row*64 + ((quad+4)^sw)*8);
    }
    #pragma unroll
    for (int z=0;z<3;z++){
      bf16x8v bfr[2][2];
      #pragma unroll
      for (int sn=0;sn<2;sn++){
        int rowb = wn*32 + sn*16 + m16;
        bfr[sn][0] = *(const bf16x8v*)(&sB[cur][z][0] + rowb*64 + ((quad  )^sw)*8);
        bfr[sn][1] = *(const bf16x8v*)(&sB[cur][z][0] + rowb*64 + ((quad+4)^sw)*8);
      }
      #pragma unroll
      for (int sm=0;sm<4;sm++)
        #pragma unroll
        for (int sn=0;sn<2;sn++){
          acc[z][sm][sn] = __builtin_amdgcn_mfma_f32_16x16x32_bf16(af[sm][0], bfr[sn][0], acc[z][sm][sn], 0,0,0);
          acc[z][sm][sn] = __builtin_amdgcn_mfma_f32_16x16x32_bf16(af[sm][1], bfr[sn][1], acc[z][sm][sn], 0,0,0);
        }
    }
    BARRIER();                            // all waves done reading buf cur
    if (kt+2 < Ec/64) stage(kt+2, cur);   // overwrite it with tile kt+2
  }
  // epilogue: C/D layout row = quad*4+r, col = lane&15
  #pragma unroll
  for (int z=0;z<3;z++){
    const float* bias = (z==0)?bq : (z==1)?bk : bv;
    unsigned short* Out = QKV + (size_t)z * (size_t)Mc * Ec;
    #pragma unroll
    for (int sm=0;sm<4;sm++){
      int row0 = bm*128 + wm*64 + sm*16 + quad*4;
      int bidx = row0 >> 11;
      #pragma unroll
      for (int sn=0;sn<2;sn++){
        int col = bn*64 + wn*32 + sn*16 + m16;
        float bb = bias[col];
        int h = col >> 6, d = col & 63;
        if (z == 2){
          int s0 = (row0 & (Sc-1)) ^ ((d & 8) ? 4 : 0);   // half-swap rows d&8 (bank fix)
          ushort4 pk;
          pk.x = f2bf(acc[z][sm][sn][0] + bb);
          pk.y = f2bf(acc[z][sm][sn][1] + bb);
          pk.z = f2bf(acc[z][sm][sn][2] + bb);
          pk.w = f2bf(acc[z][sm][sn][3] + bb);
          *(ushort4*)(Out + (((size_t)bidx*Hc + h)*Dc + d)*Sc + s0) = pk;
        } else {
          float sc_ = (z==0) ? SCL : 1.0f;   // fold 0.125*log2e into Q
          #pragma unroll
          for (int r=0;r<4;r++){
            int s = (row0 + r) & (Sc-1);
            Out[(((size_t)bidx*Hc + h)*Sc + s)*Dc + d] = f2bf((acc[z][sm][sn][r] + bb)*sc_);
          }
        }
      }
    }
  }
}

// ------------- out-proj GEMM: BM=64, grid 1024 blocks -> 4 blocks/CU (round-1-style TLP win) ----
// LDS 32 KB (sA 2x8KB + sB 2x8KB); phases still 16; per-phase MFMA halves but TLP doubles.
__global__ __launch_bounds__(256,4) void k_gemm1(const unsigned short* __restrict__ A,
                                                 const unsigned short* __restrict__ WT,
                                                 const float* __restrict__ bias,
                                                 float* __restrict__ Out){
  __shared__ unsigned short sA[2][64*64];
  __shared__ unsigned short sB[2][64*64];
  int bm = blockIdx.y, bn = blockIdx.x;
  int t = threadIdx.x, w = t>>6, lane = t&63, quad = lane>>4, m16 = lane&15;
  int wm = w>>1, wn = w&1, sw = m16 & 7;
  f32x4 acc[2][2];
  #pragma unroll
  for (int i=0;i<2;i++)
    #pragma unroll
    for (int j=0;j<2;j++) acc[i][j] = (f32x4){0.f,0.f,0.f,0.f};

  auto stage = [&](int kt, int buf){
    #pragma unroll
    for (int i=0;i<2;i++){                   // A: 64x64 = 512 chunks, 2/thread
      int cb = (w*2 + i)*64;
      int L = cb + lane;
      int row = L>>3, c = (L&7) ^ (row&7);
      GLDS(A + (size_t)(bm*64 + row)*Ec + kt*64 + c*8, &sA[buf][0] + cb*8);
    }
    #pragma unroll
    for (int i=0;i<2;i++){                   // B: 64x64 = 512 chunks, 2/thread
      int cb = (w*2 + i)*64;
      int L = cb + lane;
      int row = L>>3, c = (L&7) ^ (row&7);
      GLDS(WT + (size_t)(bn*64 + row)*Ec + kt*64 + c*8, &sB[buf][0] + cb*8);
    }
  };

  stage(0, 0);
  stage(1, 1);
  for (int kt=0; kt<Ec/64; ++kt){
    int cur = kt & 1;
    if (kt < Ec/64 - 1) VMCNT(4);         // stage(kt)'s 4 loads retired; stage(kt+1)'s flying
    else                VMCNT(0);
    BARRIER();
    bf16x8v af[2][2], bfr[2][2];
    #pragma unroll
    for (int s=0;s<2;s++){
      int row = wm*32 + s*16 + m16;
      af[s][0] = *(const bf16x8v*)(&sA[cur][0] + row*64 + ((quad  )^sw)*8);
      af[s][1] = *(const bf16x8v*)(&sA[cur][0] + row*64 + ((quad+4)^sw)*8);
    }
    #pragma unroll
    for (int sn=0;sn<2;sn++){
      int rowb = wn*32 + sn*16 + m16;
      bfr[sn][0] = *(const bf16x8v*)(&sB[cur][0] + rowb*64 + ((quad  )^sw)*8);
      bfr[sn][1] = *(const bf16x8v*)(&sB[cur][0] + rowb*64 + ((quad+4)^sw)*8);
    }
    #pragma unroll
    for (int sm=0;sm<2;sm++)
      #pragma unroll
      for (int sn=0;sn<2;sn++){
        acc[sm][sn] = __builtin_amdgcn_mfma_f32_16x16x32_bf16(af[sm][0], bfr[sn][0], acc[sm][sn], 0,0,0);
        acc[sm][sn] = __builtin_amdgcn_mfma_f32_16x16x32_bf16(af[sm][1], bfr[sn][1], acc[sm][sn], 0,0,0);
      }
    BARRIER();
    if (kt+2 < Ec/64) stage(kt+2, cur);
  }
  #pragma unroll
  for (int sm=0;sm<2;sm++){
    int row0 = bm*64 + wm*32 + sm*16 + quad*4;
    #pragma unroll
    for (int sn=0;sn<2;sn++){
      int col = bn*64 + wn*32 + sn*16 + m16;
      float bb = bias[col];
      #pragma unroll
      for (int r=0;r<4;r++)
        Out[(size_t)(row0+r)*Ec + col] = acc[sm][sn][r] + bb;
    }
  }
}

// ------------- flash attention: P in registers via K=16 PV MFMAs; conflict-free V-reads ---------
// (proven round-9 body)
__device__ __forceinline__ void attn_tile(const unsigned short* sK, const unsigned short* sVT,
                                          bf16x8v qf0, bf16x8v qf1,
                                          bf16x4v ones4, f32x4& li, f32x4* Oa,
                                          int kbase, int qw, int quad, int m16){
  int sw = m16 & 7;
  // S^T[j][q] = sum_d K[j][d] Q'[q][d]; C-layout: j=kbase+sm*16+quad*4+r, q=qw+m16
  f32x4 sc[4];
  #pragma unroll
  for (int sm=0;sm<4;sm++){
    int row = sm*16 + m16;
    bf16x8v kf0 = *(const bf16x8v*)(sK + row*64 + ((quad  )^sw)*8);
    bf16x8v kf1 = *(const bf16x8v*)(sK + row*64 + ((quad+4)^sw)*8);
    f32x4 a = (f32x4){0.f,0.f,0.f,0.f};
    a = __builtin_amdgcn_mfma_f32_16x16x32_bf16(kf0, qf0, a, 0,0,0);
    a = __builtin_amdgcn_mfma_f32_16x16x32_bf16(kf1, qf1, a, 0,0,0);
    sc[sm] = a;
  }
  // p = exp2(s); zero masked entries (diagonal tiles only)
  if (kbase + 63 > qw){
    #pragma unroll
    for (int sm=0;sm<4;sm++)
      #pragma unroll
      for (int r=0;r<4;r++){
        int kg = kbase + sm*16 + quad*4 + r;
        float p = fast_exp2(sc[sm][r]);
        sc[sm][r] = (kg <= qw + m16) ? p : 0.0f;
      }
  } else {
    #pragma unroll
    for (int sm=0;sm<4;sm++)
      #pragma unroll
      for (int r=0;r<4;r++) sc[sm][r] = fast_exp2(sc[sm][r]);
  }

  // in-lane A-frags for K=16 MFMAs: a16[sm] elem e = P[q=m16][j=sm*16+quad*4+e]
  bf16x4v a16[4];
  #pragma unroll
  for (int sm=0;sm<4;sm++){
    uint2 pk;
    pk.x = cvt_pk_bf16(sc[sm][0], sc[sm][1]);  // e0 low, e1 high
    pk.y = cvt_pk_bf16(sc[sm][2], sc[sm][3]);  // e2 low, e3 high
    a16[sm] = __builtin_bit_cast(bf16x4v, pk);
  }

  // li[q] += sum_j P[q][j] via ones-MFMA; C-layout row q=quad*4+r (matches O rows)
  #pragma unroll
  for (int sm=0;sm<4;sm++)
    li = __builtin_amdgcn_mfma_f32_16x16x16bf16_1k(a16[sm], ones4, li, 0,0,0);

  // O[q][d] += P·V ; B-frag B[k=j=quad*4+e][d=m16] = V^T[d=tt*16+m16][j=sm*16+quad*4+e]
  // half = (quad&1)^(m16>>3) matches the producer's d&8 half-swap (rowv bit3 = m16 bit3).
  int half = ((quad & 1) ^ (m16 >> 3)) * 4;
  #pragma unroll
  for (int tt=0;tt<4;tt++){
    int rowv = tt*16 + m16;
    #pragma unroll
    for (int sm=0;sm<4;sm++){
      uint2 vv = *(const uint2*)(sVT + rowv*64 + (((sm*2 + (quad>>1))^sw)*8) + half);
      Oa[tt] = __builtin_amdgcn_mfma_f32_16x16x16bf16_1k(a16[sm], __builtin_bit_cast(bf16x4v, vv), Oa[tt], 0,0,0);
    }
  }
}

// grid (32, 32) = 1024 blocks, 4 blocks/CU. XCD pin + balance mapping proven in round 2.
__global__ __launch_bounds__(256,4) void k_attn(const unsigned short* __restrict__ Qb,
                                                const unsigned short* __restrict__ Kb,
                                                const unsigned short* __restrict__ VTb,
                                                unsigned short* __restrict__ Ob){
  __shared__ unsigned short sK [2][64*64]; // [j][d], 16B chunks XOR-swizzled by row&7
  __shared__ unsigned short sVT[2][64*64]; // [d][j], same swizzle (+ producer half-swap on d&8)
  int bid = (int)blockIdx.x + 32*(int)blockIdx.y;
  int g = bid >> 3;
  int h3 = g >> 2;                          // 0..31
  int qt = (h3 & 8) ? (h3 ^ 7) : h3;        // balance involution
  int bh = (bid & 7) + ((g & 3) << 3);      // head pinned to XCD = bid%8
  size_t base = (size_t)bh * Sc * Dc;
  const unsigned short* Q  = Qb  + base;
  const unsigned short* K  = Kb  + base;
  const unsigned short* VT = VTb + base;   // [d][s]
  int t = threadIdx.x, w = t>>6, lane = t&63, quad = lane>>4, m16 = lane&15;
  int qw = qt*64 + w*16;

  bf16x8v q0 = *(const bf16x8v*)(Q + (size_t)(qw + m16)*Dc + quad*8);
  bf16x8v q1 = *(const bf16x8v*)(Q + (size_t)(qw + m16)*Dc + 32 + quad*8);

  bf16x4v ones4;
  #pragma unroll
  for (int i=0;i<4;i++) ones4[i] = (short)0x3F80;   // bf16 1.0

  f32x4 Oa[4];
  #pragma unroll
  for (int i=0;i<4;i++) Oa[i] = (f32x4){0.f,0.f,0.f,0.f};
  f32x4 li = (f32x4){0.f,0.f,0.f,0.f};

  auto stage = [&](int kt, int buf){
    int kbase = kt*64;
    #pragma unroll
    for (int i=0;i<2;i++){
      int cb = (w*2 + i)*64;              // wave-uniform chunk base
      int L = cb + lane;
      int row = L>>3, p = L&7, c = p ^ (row&7);
      GLDS(K  + (size_t)(kbase+row)*Dc + c*8,        &sK[buf][0]  + cb*8);
      GLDS(VT + (size_t)row*Sc + kbase + c*8,        &sVT[buf][0] + cb*8);
    }
  };

  stage(0, 0);
  if (qt >= 1) stage(1, 1);
  for (int kt=0; kt<=qt; ++kt){
    int cur = kt & 1;
    if (kt < qt) VMCNT(4);                // stage(kt) retired; stage(kt+1) still flying
    else         VMCNT(0);                // tail: only stage(qt) outstanding
    BARRIER();
    attn_tile(&sK[cur][0], &sVT[cur][0], q0, q1, ones4, li, Oa, kt*64, qw, quad, m16);
    BARRIER();                            // all waves done reading buf cur
    if (kt+2 <= qt) stage(kt+2, cur);     // overwrite it with tile kt+2
  }

  // epilogue: O rows s = qw+quad*4+r, cols e = h*64 + tt*16 + m16; li already per-row
  int b = bh >> 4, h = bh & 15;
  float iv[4];
  #pragma unroll
  for (int r=0;r<4;r++) iv[r] = 1.0f/li[r];
  #pragma unroll
  for (int tt=0;tt<4;tt++)
    #pragma unroll
    for (int r=0;r<4;r++){
      int e = h*64 + tt*16 + m16;
      int s = qw + quad*4 + r;
      Ob[((size_t)b*Sc + s)*Ec + e] = f2bf(Oa[tt][r]*iv[r]);
    }
}

extern "C" void kernel_launch(void* const* d_in, const int* in_sizes, int n_in,
                              void* d_out, int out_size, void* d_ws, size_t ws_size,
                              hipStream_t stream){
  const float* X  = (const float*)d_in[0];
  const float* Wq = (const float*)d_in[1];
  const float* bq = (const float*)d_in[2];
  const float* Wk = (const float*)d_in[3];
  const float* bk = (const float*)d_in[4];
  const float* Wv = (const float*)d_in[5];
  const float* bv = (const float*)d_in[6];
  const float* Wo = (const float*)d_in[7];
  const float* bo = (const float*)d_in[8];

  uint8_t* ws = (uint8_t*)d_ws;
  unsigned short* Xb  = (unsigned short*)(ws);                    // 8 MB
  unsigned short* WT4 = (unsigned short*)(ws + (size_t)(8u<<20)); // 8 MB (WqT,WkT,WvT,WoT)
  unsigned short* QKV = (unsigned short*)(ws + (size_t)(16u<<20));// 24 MB (Q,K,V^T)
  unsigned short* ATT = (unsigned short*)(ws + (size_t)(40u<<20));// 8 MB

  k_prep<<<dim3(5120), 256, 0, stream>>>(X, Xb, Wq, Wk, Wv, Wo, WT4);
  k_qkv<<<dim3(16,32), 256, 0, stream>>>(Xb, WT4, bq, bk, bv, QKV);
  k_attn<<<dim3(32,32), 256, 0, stream>>>(QKV, QKV + (size_t)Mc*Ec, QKV + 2*(size_t)Mc*Ec, ATT);
  k_gemm1<<<dim3(16,64), 256, 0, stream>>>(ATT, WT4 + (size_t)3*Ec*Ec, bo, (float*)d_out);
}